// Round 7
// baseline (375.269 us; speedup 1.0000x reference)
//
#include <hip/hip_runtime.h>
#include <math.h>

#define NGRAPH 1000
#define NPG    100
#define EPG    1600
#define NF     32
#define NC     10
#define KP     30
#define OUTL   16
#define INL    97
#define NITER  3

#define NTV    512    // main kernel block size
#define NTF    1024   // fused fallback block size

#define XSTR   36     // xbuf/hs row stride (floats)
#define FSTR   100    // fused: feat row stride
#define HSTR   36
#define PSTR   164    // priors row stride (floats)
#define LQ     24
#define CSRMAX 1920   // padded CSR capacity (<= 1600 + 3*100)
#define ZROW   (NPG * XSTR)  // 3600: zero-row offset for padding

#define WS_EDGES_BYTES ((size_t)NGRAPH * EPG * 4)
#define WS_CAPT_FLOATS (NC * LQ * OUTL * 4)
#define WS_CAPL_FLOATS (NC * OUTL)
#define WS_CAP_BYTES   ((size_t)(WS_CAPT_FLOATS + WS_CAPL_FLOATS) * 4)
#define WS_FEATG_OFF   (WS_EDGES_BYTES + WS_CAP_BYTES)
#define WS_FEATG_BYTES ((size_t)NGRAPH * NPG * 100 * 4)
#define WS_FULL_BYTES  (WS_FEATG_OFF + WS_FEATG_BYTES)

#define PIDX(i, c) ((i) * PSTR + (c) * OUTL)

__device__ __forceinline__ float4 ld4(const float* p) { return *reinterpret_cast<const float4*>(p); }
__device__ __forceinline__ void st4(float* p, float4 v) { *reinterpret_cast<float4*>(p) = v; }
__device__ __forceinline__ float dot4(float4 a, float4 b) { return a.x*b.x + a.y*b.y + a.z*b.z + a.w*b.w; }
__device__ __forceinline__ float tanh_fast(float x) {
  float e = __expf(2.f * x);
  return 1.f - 2.f / (e + 1.f);
}

// ---- pre-kernel 1: transpose edges [k][g] -> [g][k], pack local (src<<8|dst)
__global__ void prek_edges(const int* __restrict__ esrc, const int* __restrict__ edst,
                           unsigned int* __restrict__ wsE) {
  __shared__ unsigned int t[64][65];
  const int kb = blockIdx.x % (EPG / 64);
  const int gb = blockIdx.x / (EPG / 64);
  const int lane = threadIdx.x & 63;
  const int row  = threadIdx.x >> 6;
  #pragma unroll
  for (int r = row; r < 64; r += 4) {
    int k = kb * 64 + r;
    int g = gb * 64 + lane;
    if (g < NGRAPH) {
      int idx = k * NGRAPH + g;
      int si = esrc[idx] - g * NPG;
      int di = edst[idx] - g * NPG;
      t[r][lane] = (unsigned int)((si << 8) | di);
    }
  }
  __syncthreads();
  #pragma unroll
  for (int r = row; r < 64; r += 4) {
    int g = gb * 64 + r;
    int k = kb * 64 + lane;
    if (g < NGRAPH) wsE[(size_t)g * EPG + k] = t[lane][r];
  }
}

// ---- pre-kernel 2: Wcap[c][e][l] -> capT[c][lq][e][4] + capL[c][e] (l=96)
__global__ void prek_cap(const float* __restrict__ Wcap, float* __restrict__ capT,
                         float* __restrict__ capL) {
  int o = blockIdx.x * 256 + threadIdx.x;
  if (o < WS_CAPT_FLOATS) {
    int j  = o & 3;
    int e  = (o >> 2) & 15;
    int lq = (o >> 6) % LQ;
    int c  = (o >> 6) / LQ;
    capT[o] = Wcap[(c * OUTL + e) * INL + lq * 4 + j];
  }
  if (o < WS_CAPL_FLOATS) capL[o] = Wcap[o * INL + 96];
}

// ============================ v7: v6 with AGG coverage fix ============================
struct SMemV6 {
  union {
    struct {                             // phase A
      float xbuf[NPG * XSTR];            // 14400
      float hs[(NPG + 1) * XSTR];        // 14544 (row 100 = zeros for CSR padding)
      float W[NF * NF];                  // 4096
      float bias2[2][NF];                // 256
      unsigned short csr16[CSRMAX];      // 3840 : src*XSTR offsets, padded to x4 per dst
      int cnt[NPG];                      // 400
      float dinv[NPG];                   // 400
      float col96[NPG];                  // 400
      int ptr[NPG + 1];                  // 404
    } a;                                 // 38740 B
    struct {                             // phase B
      float feat30[KP * 100];            // 12000
      float priors[KP * PSTR];           // 19680
      float prsq[KP * NC];               // 1200
      float simbuf[KP * NC];             // 1200
      float outv[NC * OUTL];             // 640
    } b;
  } u;
  int order[KP];                         // 120
};                                       // ~38.9 KB -> 4 blocks/CU

__global__ __launch_bounds__(NTV, 8) void gcn_caps_v7(
    const float* __restrict__ x,
    const unsigned int* __restrict__ wsE,
    const float* __restrict__ W1, const float* __restrict__ b1,
    const float* __restrict__ W2, const float* __restrict__ b2,
    const float* __restrict__ W3, const float* __restrict__ b3,
    const float* __restrict__ W4, const float* __restrict__ b4,
    const float* __restrict__ capT, const float* __restrict__ capL,
    float* __restrict__ featG,
    float* __restrict__ out)
{
  extern __shared__ char smraw[];
  SMemV6& s = *reinterpret_cast<SMemV6*>(smraw);
  const int g = blockIdx.x;
  const int tid = threadIdx.x;

  // A1: zero counters + zero pad-row of hs, stage W1/b1, stage x->xbuf
  if (tid < NPG) s.u.a.cnt[tid] = 0;
  if (tid >= 128 && tid < 128 + XSTR) s.u.a.hs[ZROW + (tid - 128)] = 0.f;
  for (int i = tid; i < NF * NF; i += NTV) s.u.a.W[i] = W1[i];
  if (tid < NF) s.u.a.bias2[0][tid] = b1[tid];
  const float4* xr = reinterpret_cast<const float4*>(x + (size_t)g * NPG * NF);
  for (int o = tid; o < NPG * 8; o += NTV) {
    int node = o >> 3, kq = o & 7;
    st4(&s.u.a.xbuf[node * XSTR + kq * 4], xr[o]);
  }
  __syncthreads();

  // A2: degree count
  const unsigned int* eg = wsE + (size_t)g * EPG;
  for (int k = tid; k < EPG; k += NTV) atomicAdd(&s.u.a.cnt[eg[k] & 0xFF], 1);
  __syncthreads();

  // A3: exclusive scan over PADDED counts (multiple of 4 per node)
  if (tid < 64) {
    int j = tid;
    int r0 = (2 * j < NPG) ? s.u.a.cnt[2 * j] : 0;
    int r1 = (2 * j + 1 < NPG) ? s.u.a.cnt[2 * j + 1] : 0;
    int p0 = (r0 + 3) & ~3, p1 = (r1 + 3) & ~3;
    int t = p0 + p1;
    int run = t;
    #pragma unroll
    for (int off = 1; off < 64; off <<= 1) {
      int u = __shfl_up(run, off);
      if (j >= off) run += u;
    }
    int excl = run - t;
    if (2 * j < NPG) s.u.a.ptr[2 * j] = excl;
    if (2 * j + 1 < NPG) s.u.a.ptr[2 * j + 1] = excl + p0;
    if (j == 63) s.u.a.ptr[NPG] = run;
  }
  __syncthreads();
  if (tid < NPG) {
    int deg = s.u.a.cnt[tid];
    int p0 = s.u.a.ptr[tid], p1 = s.u.a.ptr[tid + 1];
    s.u.a.dinv[tid] = rsqrtf((float)deg + 1.0f);
    s.u.a.cnt[tid] = p0;                       // fill cursor
    for (int j = p0 + deg; j < p1; ++j) s.u.a.csr16[j] = (unsigned short)ZROW;  // pad -> zero row
  }
  __syncthreads();

  // A4: CSR fill (offsets pre-multiplied by XSTR)
  for (int k = tid; k < EPG; k += NTV) {
    unsigned int p = eg[k];
    int pos = atomicAdd(&s.u.a.cnt[p & 0xFF], 1);
    s.u.a.csr16[pos] = (unsigned short)(((p >> 8) & 0xFF) * XSTR);
  }
  __syncthreads();

  float* fG = featG + (size_t)g * NPG * 100;

  // A5: three 32-wide GCN layers
  for (int l = 0; l < 3; ++l) {
    // GEMM, 4-node register-blocked: thread = (nd in [0,25), cq); nodes nd+25n
    if (tid < 25 * 8) {
      int nd = tid >> 3, cq = tid & 7;
      float4 ac0 = make_float4(0,0,0,0), ac1 = ac0, ac2 = ac0, ac3 = ac0;
      #pragma unroll
      for (int kq = 0; kq < 8; ++kq) {
        float4 a0, a1, a2, a3;
        if (l == 0) {
          a0 = xr[(nd     ) * 8 + kq]; a1 = xr[(nd + 25) * 8 + kq];
          a2 = xr[(nd + 50) * 8 + kq]; a3 = xr[(nd + 75) * 8 + kq];
        } else {
          a0 = ld4(&s.u.a.xbuf[(nd     ) * XSTR + kq * 4]);
          a1 = ld4(&s.u.a.xbuf[(nd + 25) * XSTR + kq * 4]);
          a2 = ld4(&s.u.a.xbuf[(nd + 50) * XSTR + kq * 4]);
          a3 = ld4(&s.u.a.xbuf[(nd + 75) * XSTR + kq * 4]);
        }
        const float v0[4] = {a0.x, a0.y, a0.z, a0.w};
        const float v1[4] = {a1.x, a1.y, a1.z, a1.w};
        const float v2[4] = {a2.x, a2.y, a2.z, a2.w};
        const float v3[4] = {a3.x, a3.y, a3.z, a3.w};
        #pragma unroll
        for (int j = 0; j < 4; ++j) {
          float4 w4 = ld4(&s.u.a.W[(kq * 4 + j) * NF + cq * 4]);
          ac0.x += v0[j]*w4.x; ac0.y += v0[j]*w4.y; ac0.z += v0[j]*w4.z; ac0.w += v0[j]*w4.w;
          ac1.x += v1[j]*w4.x; ac1.y += v1[j]*w4.y; ac1.z += v1[j]*w4.z; ac1.w += v1[j]*w4.w;
          ac2.x += v2[j]*w4.x; ac2.y += v2[j]*w4.y; ac2.z += v2[j]*w4.z; ac2.w += v2[j]*w4.w;
          ac3.x += v3[j]*w4.x; ac3.y += v3[j]*w4.y; ac3.z += v3[j]*w4.z; ac3.w += v3[j]*w4.w;
        }
      }
      float d0 = s.u.a.dinv[nd], d1 = s.u.a.dinv[nd + 25];
      float d2 = s.u.a.dinv[nd + 50], d3 = s.u.a.dinv[nd + 75];
      ac0.x*=d0; ac0.y*=d0; ac0.z*=d0; ac0.w*=d0;
      ac1.x*=d1; ac1.y*=d1; ac1.z*=d1; ac1.w*=d1;
      ac2.x*=d2; ac2.y*=d2; ac2.z*=d2; ac2.w*=d2;
      ac3.x*=d3; ac3.y*=d3; ac3.z*=d3; ac3.w*=d3;
      st4(&s.u.a.hs[(nd     ) * XSTR + cq * 4], ac0);
      st4(&s.u.a.hs[(nd + 25) * XSTR + cq * 4], ac1);
      st4(&s.u.a.hs[(nd + 50) * XSTR + cq * 4], ac2);
      st4(&s.u.a.hs[(nd + 75) * XSTR + cq * 4], ac3);
    }
    __syncthreads();

    // prefetch next weights (AGG never reads W)
    if (l == 0) {
      for (int i = tid; i < NF * NF; i += NTV) s.u.a.W[i] = W2[i];
      if (tid < NF) s.u.a.bias2[1][tid] = b2[tid];
    } else if (l == 1) {
      for (int i = tid; i < NF * NF; i += NTV) s.u.a.W[i] = W3[i];
      if (tid < NF) s.u.a.bias2[0][tid] = b3[tid];
    } else {
      if (tid < NF) s.u.a.W[tid] = W4[tid];
      if (tid == NTV - 1) s.u.a.bias2[1][0] = b4[0];
    }

    // AGG (grid-stride: 800 items on 512 threads — the v6 bug was `if (tid<800)`)
    for (int o = tid; o < NPG * 8; o += NTV) {
      int d = o >> 3, fq4 = (o & 7) * 4;
      const float* bc = s.u.a.bias2[l & 1];
      float4 bq = ld4(&bc[fq4]);
      float4 r = ld4(&s.u.a.hs[d * XSTR + fq4]);   // self term
      int p0 = s.u.a.ptr[d], p1 = s.u.a.ptr[d + 1];
      for (int idx = p0; idx < p1; idx += 4) {
        uint2 c2 = *reinterpret_cast<const uint2*>(&s.u.a.csr16[idx]);
        int o0 = c2.x & 0xFFFF, o1 = c2.x >> 16;
        int o2 = c2.y & 0xFFFF, o3 = c2.y >> 16;
        float4 h0 = ld4(&s.u.a.hs[o0 + fq4]);
        float4 h1 = ld4(&s.u.a.hs[o1 + fq4]);
        float4 h2 = ld4(&s.u.a.hs[o2 + fq4]);
        float4 h3 = ld4(&s.u.a.hs[o3 + fq4]);
        r.x += (h0.x + h1.x) + (h2.x + h3.x);
        r.y += (h0.y + h1.y) + (h2.y + h3.y);
        r.z += (h0.z + h1.z) + (h2.z + h3.z);
        r.w += (h0.w + h1.w) + (h2.w + h3.w);
      }
      float di = s.u.a.dinv[d];
      float4 oo;
      oo.x = tanh_fast(di * r.x + bq.x);
      oo.y = tanh_fast(di * r.y + bq.y);
      oo.z = tanh_fast(di * r.z + bq.z);
      oo.w = tanh_fast(di * r.w + bq.w);
      st4(&s.u.a.xbuf[d * XSTR + fq4], oo);        // next layer input
      st4(&fG[d * 100 + l * NF + fq4], oo);        // stream to global
    }
    __syncthreads();
  }

  // A6: layer 4 (1-wide)
  if (tid < NPG) {
    float a = 0.f;
    #pragma unroll
    for (int kq = 0; kq < 8; ++kq)
      a += dot4(ld4(&s.u.a.xbuf[tid * XSTR + kq * 4]), ld4(&s.u.a.W[kq * 4]));
    s.u.a.hs[tid * XSTR] = a * s.u.a.dinv[tid];
  }
  __syncthreads();
  if (tid < NPG) {
    float r = s.u.a.hs[tid * XSTR];
    int p0 = s.u.a.ptr[tid], p1 = s.u.a.ptr[tid + 1];
    for (int idx = p0; idx < p1; ++idx) r += s.u.a.hs[s.u.a.csr16[idx]];  // pads add hs[ZROW]=0
    float c96 = tanh_fast(s.u.a.dinv[tid] * r + s.u.a.bias2[1][0]);
    s.u.a.col96[tid] = c96;
    fG[tid * 100 + 96] = c96;
  }
  __syncthreads();

  // A7: stable top-30 by col96 desc; 4 threads/node
  if (tid < NPG * 4) {
    int i = tid >> 2, p = tid & 3;
    float vv = s.u.a.col96[i];
    int j0 = p * 25, j1 = j0 + 25;
    int rank = 0;
    for (int j = j0; j < j1; ++j) {
      float vj = s.u.a.col96[j];
      rank += (vj > vv) || (vj == vv && j < i);
    }
    rank += __shfl_xor(rank, 1);
    rank += __shfl_xor(rank, 2);
    if (p == 0 && rank < KP) s.order[rank] = i;
  }
  __syncthreads();

  // B1: gather 30 selected rows from featG
  for (int idx = tid; idx < KP * 100; idx += NTV) {
    int r = idx / 100, c = idx - r * 100;
    s.u.b.feat30[idx] = featG[((size_t)g * NPG + s.order[r]) * 100 + c];
  }
  __syncthreads();

  // B2: priors, (c,e)-major with 15-i register blocking; W read once per thread/lq
  if (tid < NC * OUTL * 2) {
    int c = tid >> 5;
    int r = tid & 31;
    int e = r >> 1;
    int i0 = (r & 1) * 15;
    float acc[15];
    #pragma unroll
    for (int ii = 0; ii < 15; ++ii) acc[ii] = 0.f;
    for (int lq = 0; lq < LQ; ++lq) {
      float4 w4 = ld4(capT + ((c * LQ + lq) * OUTL + e) * 4);
      #pragma unroll
      for (int ii = 0; ii < 15; ++ii) {
        float4 f4 = ld4(&s.u.b.feat30[(i0 + ii) * 100 + lq * 4]);
        acc[ii] += dot4(f4, w4);
      }
    }
    float wl = capL[c * OUTL + e];
    #pragma unroll
    for (int ii = 0; ii < 15; ++ii)
      acc[ii] += s.u.b.feat30[(i0 + ii) * 100 + 96] * wl;
    #pragma unroll
    for (int ii = 0; ii < 15; ++ii)
      s.u.b.priors[PIDX(i0 + ii, c) + e] = acc[ii];
  }
  __syncthreads();

  // B3: pr_sq + out init
  if (tid < KP * NC) {
    int i = tid / NC, c = tid % NC;
    const float* pr = &s.u.b.priors[PIDX(i, c)];
    float a = 0.f;
    #pragma unroll
    for (int eq = 0; eq < 4; ++eq) { float4 p = ld4(pr + eq * 4); a += dot4(p, p); }
    s.u.b.prsq[tid] = a;
  }
  if (tid < NC * OUTL) {
    int c = tid >> 4, e = tid & 15;
    float a = 0.f;
    #pragma unroll
    for (int i = 0; i < KP; ++i) a += s.u.b.priors[PIDX(i, c) + e];
    s.u.b.outv[tid] = a * (1.0f / KP);
  }
  __syncthreads();

  // B4: routing, 2 barriers/iter
  for (int it = 0; it < NITER; ++it) {
    if (tid < KP * NC) {
      int i = tid / NC, c = tid % NC;
      const float* pr = &s.u.b.priors[PIDX(i, c)];
      const float* ov = &s.u.b.outv[c * OUTL];
      float xy = 0.f, oq = 0.f;
      #pragma unroll
      for (int eq = 0; eq < 4; ++eq) {
        float4 p = ld4(pr + eq * 4);
        float4 o = ld4(ov + eq * 4);
        xy += dot4(p, o); oq += dot4(o, o);
      }
      s.u.b.simbuf[tid] = xy / (s.u.b.prsq[tid] + oq - xy);
    }
    __syncthreads();
    if (tid < NC * OUTL) {
      int c = tid >> 4, e = tid & 15;
      float m = -1e30f;
      #pragma unroll
      for (int i = 0; i < KP; ++i) m = fmaxf(m, s.u.b.simbuf[i * NC + c]);
      float ss = 0.f, a = 0.f;
      #pragma unroll
      for (int i = 0; i < KP; ++i) {
        float w = __expf(s.u.b.simbuf[i * NC + c] - m);
        ss += w;
        a += w * s.u.b.priors[PIDX(i, c) + e];
      }
      s.u.b.outv[tid] = a / ss;
    }
    __syncthreads();
  }

  // B5: classes = ||out||
  if (tid < NC) {
    const float* ov = &s.u.b.outv[tid * OUTL];
    float a = 0.f;
    #pragma unroll
    for (int eq = 0; eq < 4; ++eq) { float4 o = ld4(ov + eq * 4); a += dot4(o, o); }
    out[(size_t)g * NC + tid] = sqrtf(a);
  }
}

// ==================== fused fallback (proven R4 kernel, 81KB LDS) ====================
struct SMemF {
  float feat[NPG * FSTR];
  union {
    unsigned short epack[EPG];
    float priors[KP * PSTR];
  } u;
  union {
    float hs[NPG * HSTR];
    struct {
      float prsq[KP * NC];
      float simbuf[KP * NC];
      float outv[NC * OUTL];
      float smax[NC];
      float ssum[NC];
      int   order[KP];
    } r;
  } v;
  float W[NF * NF];
  float bias2[2][NF];
  unsigned char csr[EPG];
  int ptr[NPG + 1];
  int cnt[NPG];
  float dinv[NPG];
};

template <bool WSE, bool WSC>
__global__ __launch_bounds__(NTF, 8) void gcn_caps_fused(
    const float* __restrict__ x,
    const int* __restrict__ esrc, const int* __restrict__ edst,
    const float* __restrict__ W1, const float* __restrict__ b1,
    const float* __restrict__ W2, const float* __restrict__ b2,
    const float* __restrict__ W3, const float* __restrict__ b3,
    const float* __restrict__ W4, const float* __restrict__ b4,
    const float* __restrict__ Wcap,
    const unsigned int* __restrict__ wsE,
    const float* __restrict__ capT, const float* __restrict__ capL,
    float* __restrict__ out)
{
  extern __shared__ char smem_raw[];
  SMemF& s = *reinterpret_cast<SMemF*>(smem_raw);
  const int g = blockIdx.x;
  const int tid = threadIdx.x;

  if (tid < NPG) s.cnt[tid] = 0;
  for (int i = tid; i < NF * NF; i += NTF) s.W[i] = W1[i];
  if (tid < NF) s.bias2[0][tid] = b1[tid];
  __syncthreads();

  if (WSE) {
    const unsigned int* eg = wsE + (size_t)g * EPG;
    for (int k = tid; k < EPG; k += NTF) {
      unsigned int p = eg[k];
      s.u.epack[k] = (unsigned short)p;
      atomicAdd(&s.cnt[p & 0xFF], 1);
    }
  } else {
    for (int k = tid; k < EPG; k += NTF) {
      int si = esrc[g + k * NGRAPH] - g * NPG;
      int di = edst[g + k * NGRAPH] - g * NPG;
      s.u.epack[k] = (unsigned short)((si << 8) | di);
      atomicAdd(&s.cnt[di], 1);
    }
  }
  __syncthreads();

  if (tid < 64) {
    int j = tid;
    int a0 = (2 * j < NPG) ? s.cnt[2 * j] : 0;
    int a1 = (2 * j + 1 < NPG) ? s.cnt[2 * j + 1] : 0;
    int t = a0 + a1;
    int run = t;
    #pragma unroll
    for (int off = 1; off < 64; off <<= 1) {
      int u = __shfl_up(run, off);
      if (j >= off) run += u;
    }
    int excl = run - t;
    if (2 * j < NPG) s.ptr[2 * j] = excl;
    if (2 * j + 1 < NPG) s.ptr[2 * j + 1] = excl + a0;
    if (j == 63) s.ptr[NPG] = run;
  }
  __syncthreads();
  if (tid < NPG) {
    s.dinv[tid] = rsqrtf((float)s.cnt[tid] + 1.0f);
    s.cnt[tid] = s.ptr[tid];
  }
  __syncthreads();

  for (int k = tid; k < EPG; k += NTF) {
    int pk = s.u.epack[k];
    int pos = atomicAdd(&s.cnt[pk & 0xFF], 1);
    s.csr[pos] = (unsigned char)(pk >> 8);
  }
  __syncthreads();

  const float4* xr = reinterpret_cast<const float4*>(x + (size_t)g * NPG * NF);
  for (int l = 0; l < 3; ++l) {
    if (tid < NPG * 8) {
      int node = tid >> 3, cq = tid & 7;
      float4 acc = make_float4(0.f, 0.f, 0.f, 0.f);
      #pragma unroll
      for (int kq = 0; kq < 8; ++kq) {
        float4 a4 = (l == 0) ? xr[node * 8 + kq]
                             : ld4(&s.feat[node * FSTR + (l - 1) * NF + kq * 4]);
        const float av[4] = {a4.x, a4.y, a4.z, a4.w};
        #pragma unroll
        for (int j = 0; j < 4; ++j) {
          float4 w4 = ld4(&s.W[(kq * 4 + j) * NF + cq * 4]);
          acc.x += av[j] * w4.x; acc.y += av[j] * w4.y;
          acc.z += av[j] * w4.z; acc.w += av[j] * w4.w;
        }
      }
      float di = s.dinv[node];
      acc.x *= di; acc.y *= di; acc.z *= di; acc.w *= di;
      st4(&s.v.hs[node * HSTR + ((cq ^ (node >> 3)) & 7) * 4], acc);
    }
    __syncthreads();

    if (l == 0) {
      for (int i = tid; i < NF * NF; i += NTF) s.W[i] = W2[i];
      if (tid < NF) s.bias2[1][tid] = b2[tid];
    } else if (l == 1) {
      for (int i = tid; i < NF * NF; i += NTF) s.W[i] = W3[i];
      if (tid < NF) s.bias2[0][tid] = b3[tid];
    } else {
      if (tid < NF) s.W[tid] = W4[tid];
      if (tid == NTF - 1) s.bias2[1][0] = b4[0];
    }

    if (tid < NPG * 8) {
      int d = tid >> 3, fq = tid & 7;
      const float* bc = s.bias2[l & 1];
      float4 b4q = ld4(&bc[fq * 4]);
      float4 r = ld4(&s.v.hs[d * HSTR + ((fq ^ (d >> 3)) & 7) * 4]);
      int p0 = s.ptr[d], p1 = s.ptr[d + 1];
      int idx = p0;
      for (; idx + 1 < p1; idx += 2) {
        int sc0 = s.csr[idx], sc1 = s.csr[idx + 1];
        float4 h0 = ld4(&s.v.hs[sc0 * HSTR + ((fq ^ (sc0 >> 3)) & 7) * 4]);
        float4 h1 = ld4(&s.v.hs[sc1 * HSTR + ((fq ^ (sc1 >> 3)) & 7) * 4]);
        r.x += h0.x + h1.x; r.y += h0.y + h1.y;
        r.z += h0.z + h1.z; r.w += h0.w + h1.w;
      }
      if (idx < p1) {
        int sc = s.csr[idx];
        float4 hq = ld4(&s.v.hs[sc * HSTR + ((fq ^ (sc >> 3)) & 7) * 4]);
        r.x += hq.x; r.y += hq.y; r.z += hq.z; r.w += hq.w;
      }
      float di = s.dinv[d];
      float4 o;
      o.x = tanh_fast(di * r.x + b4q.x);
      o.y = tanh_fast(di * r.y + b4q.y);
      o.z = tanh_fast(di * r.z + b4q.z);
      o.w = tanh_fast(di * r.w + b4q.w);
      st4(&s.feat[d * FSTR + l * NF + fq * 4], o);
    }
    __syncthreads();
  }

  float* hsf = s.v.hs;
  if (tid < NPG) {
    float a = 0.f;
    #pragma unroll
    for (int kq = 0; kq < 8; ++kq)
      a += dot4(ld4(&s.feat[tid * FSTR + 64 + kq * 4]), ld4(&s.W[kq * 4]));
    hsf[tid] = a * s.dinv[tid];
  }
  __syncthreads();
  if (tid < NPG) {
    float r = hsf[tid];
    int p0 = s.ptr[tid], p1 = s.ptr[tid + 1];
    for (int idx = p0; idx < p1; ++idx) r += hsf[s.csr[idx]];
    s.feat[tid * FSTR + 96] = tanh_fast(s.dinv[tid] * r + s.bias2[1][0]);
  }
  __syncthreads();

  if (tid < NPG * 8) {
    int i = tid >> 3, p = tid & 7;
    float vv = s.feat[i * FSTR + 96];
    int j0 = p * 13, j1 = min(NPG, j0 + 13);
    int rank = 0;
    for (int j = j0; j < j1; ++j) {
      float vj = s.feat[j * FSTR + 96];
      rank += (vj > vv) || (vj == vv && j < i);
    }
    rank += __shfl_xor(rank, 1);
    rank += __shfl_xor(rank, 2);
    rank += __shfl_xor(rank, 4);
    if (p == 0 && rank < KP) s.v.r.order[rank] = i;
  }
  __syncthreads();

  if (tid < KP * OUTL) {
    int i = tid >> 4, e = tid & 15;
    int row = s.v.r.order[i] * FSTR;
    float acc[NC];
    #pragma unroll
    for (int c = 0; c < NC; ++c) acc[c] = 0.f;
    if (WSC) {
      for (int lq = 0; lq < LQ; ++lq) {
        float4 f4 = ld4(&s.feat[row + lq * 4]);
        #pragma unroll
        for (int c = 0; c < NC; ++c) {
          float4 w4 = ld4(capT + ((c * LQ + lq) * OUTL + e) * 4);
          acc[c] += dot4(f4, w4);
        }
      }
      float xl = s.feat[row + 96];
      #pragma unroll
      for (int c = 0; c < NC; ++c) acc[c] += xl * capL[c * OUTL + e];
    } else {
      for (int c = 0; c < NC; ++c) {
        float a = 0.f;
        for (int l = 0; l < INL; ++l) a += s.feat[row + l] * Wcap[(c * OUTL + e) * INL + l];
        acc[c] = a;
      }
    }
    #pragma unroll
    for (int c = 0; c < NC; ++c) s.u.priors[PIDX(i, c) + e] = acc[c];
  }
  __syncthreads();

  if (tid < KP * NC) {
    int i = tid / NC, c = tid % NC;
    const float* pr = &s.u.priors[PIDX(i, c)];
    float a = 0.f;
    #pragma unroll
    for (int eq = 0; eq < 4; ++eq) { float4 p = ld4(pr + eq * 4); a += dot4(p, p); }
    s.v.r.prsq[tid] = a;
  }
  if (tid < NC * OUTL) {
    int c = tid >> 4, e = tid & 15;
    float a = 0.f;
    #pragma unroll
    for (int i = 0; i < KP; ++i) a += s.u.priors[PIDX(i, c) + e];
    s.v.r.outv[tid] = a * (1.0f / KP);
  }
  __syncthreads();

  for (int it = 0; it < NITER; ++it) {
    if (tid < KP * NC) {
      int i = tid / NC, c = tid % NC;
      const float* pr = &s.u.priors[PIDX(i, c)];
      const float* ov = &s.v.r.outv[c * OUTL];
      float xy = 0.f, oq = 0.f;
      #pragma unroll
      for (int eq = 0; eq < 4; ++eq) {
        float4 p = ld4(pr + eq * 4);
        float4 o = ld4(ov + eq * 4);
        xy += dot4(p, o); oq += dot4(o, o);
      }
      s.v.r.simbuf[tid] = xy / (s.v.r.prsq[tid] + oq - xy);
    }
    __syncthreads();
    if (tid < NC) {
      float m = -1e30f;
      #pragma unroll
      for (int i = 0; i < KP; ++i) m = fmaxf(m, s.v.r.simbuf[i * NC + tid]);
      float ss = 0.f;
      #pragma unroll
      for (int i = 0; i < KP; ++i) ss += __expf(s.v.r.simbuf[i * NC + tid] - m);
      s.v.r.smax[tid] = m;
      s.v.r.ssum[tid] = 1.f / ss;
    }
    __syncthreads();
    if (tid < NC * OUTL) {
      int c = tid >> 4, e = tid & 15;
      float m = s.v.r.smax[c], is = s.v.r.ssum[c], a = 0.f;
      #pragma unroll
      for (int i = 0; i < KP; ++i)
        a += __expf(s.v.r.simbuf[i * NC + c] - m) * s.u.priors[PIDX(i, c) + e];
      s.v.r.outv[tid] = a * is;
    }
    __syncthreads();
  }

  if (tid < NC) {
    const float* ov = &s.v.r.outv[tid * OUTL];
    float a = 0.f;
    #pragma unroll
    for (int eq = 0; eq < 4; ++eq) { float4 o = ld4(ov + eq * 4); a += dot4(o, o); }
    out[(size_t)g * NC + tid] = sqrtf(a);
  }
}

extern "C" void kernel_launch(void* const* d_in, const int* in_sizes, int n_in,
                              void* d_out, int out_size, void* d_ws, size_t ws_size,
                              hipStream_t stream) {
  const float* x    = (const float*)d_in[0];
  const int*   esrc = (const int*)d_in[1];
  const int*   edst = (const int*)d_in[2];
  const float* W1 = (const float*)d_in[4];
  const float* b1 = (const float*)d_in[5];
  const float* W2 = (const float*)d_in[6];
  const float* b2 = (const float*)d_in[7];
  const float* W3 = (const float*)d_in[8];
  const float* b3 = (const float*)d_in[9];
  const float* W4 = (const float*)d_in[10];
  const float* b4 = (const float*)d_in[11];
  const float* Wcap = (const float*)d_in[12];
  float* outp = (float*)d_out;

  const bool full = ws_size >= WS_FULL_BYTES;
  const bool wse  = ws_size >= WS_EDGES_BYTES + WS_CAP_BYTES;
  const bool wsc  = ws_size >= WS_CAP_BYTES;

  unsigned int* wsE = (unsigned int*)d_ws;
  float* capT = (full || wse) ? (float*)((char*)d_ws + WS_EDGES_BYTES) : (float*)d_ws;
  float* capL = capT + WS_CAPT_FLOATS;
  float* featG = (float*)((char*)d_ws + WS_FEATG_OFF);

  if (full) {
    (void)hipFuncSetAttribute((const void*)gcn_caps_v7,
                              hipFuncAttributeMaxDynamicSharedMemorySize, (int)sizeof(SMemV6));
    prek_edges<<<(EPG / 64) * 16, 256, 0, stream>>>(esrc, edst, wsE);
    prek_cap<<<(WS_CAPT_FLOATS + 255) / 256, 256, 0, stream>>>(Wcap, capT, capL);
    gcn_caps_v7<<<NGRAPH, NTV, sizeof(SMemV6), stream>>>(
        x, wsE, W1, b1, W2, b2, W3, b3, W4, b4, capT, capL, featG, outp);
  } else if (wse) {
    (void)hipFuncSetAttribute((const void*)gcn_caps_fused<true, true>,
                              hipFuncAttributeMaxDynamicSharedMemorySize, (int)sizeof(SMemF));
    prek_edges<<<(EPG / 64) * 16, 256, 0, stream>>>(esrc, edst, wsE);
    prek_cap<<<(WS_CAPT_FLOATS + 255) / 256, 256, 0, stream>>>(Wcap, capT, capL);
    gcn_caps_fused<true, true><<<NGRAPH, NTF, sizeof(SMemF), stream>>>(
        x, esrc, edst, W1, b1, W2, b2, W3, b3, W4, b4, Wcap, wsE, capT, capL, outp);
  } else if (wsc) {
    (void)hipFuncSetAttribute((const void*)gcn_caps_fused<false, true>,
                              hipFuncAttributeMaxDynamicSharedMemorySize, (int)sizeof(SMemF));
    prek_cap<<<(WS_CAPT_FLOATS + 255) / 256, 256, 0, stream>>>(Wcap, capT, capL);
    gcn_caps_fused<false, true><<<NGRAPH, NTF, sizeof(SMemF), stream>>>(
        x, esrc, edst, W1, b1, W2, b2, W3, b3, W4, b4, Wcap, wsE, capT, capL, outp);
  } else {
    (void)hipFuncSetAttribute((const void*)gcn_caps_fused<false, false>,
                              hipFuncAttributeMaxDynamicSharedMemorySize, (int)sizeof(SMemF));
    gcn_caps_fused<false, false><<<NGRAPH, NTF, sizeof(SMemF), stream>>>(
        x, esrc, edst, W1, b1, W2, b2, W3, b3, W4, b4, Wcap, wsE, capT, capL, outp);
  }
}

// Round 8
// 102.417 us; speedup vs baseline: 3.6641x; 3.6641x over previous
//
#include <hip/hip_runtime.h>
#include <math.h>

#define NGRAPH 1000
#define NPG    100
#define EPG    1600
#define NF     32
#define NC     10
#define KP     30
#define OUTL   16
#define INL    97
#define NITER  3

#define NTV    512    // main kernel block size
#define NTF    1024   // fused fallback block size

#define XSTR   36     // hs row stride (floats)
#define FSTR   100    // feat row stride (floats)
#define HSTR   36
#define PSTR   164    // priors row stride (floats)
#define LQ     24
#define CSRMAX 1920   // padded CSR capacity (1600 + 3*100 <= 1920)
#define ZROW   (NPG * XSTR)  // 3600: zero-row offset for padding

#define WS_EDGES_BYTES ((size_t)NGRAPH * EPG * 4)
#define WS_CAPT_FLOATS (NC * LQ * OUTL * 4)
#define WS_CAPL_FLOATS (NC * OUTL)
#define WS_CAP_BYTES   ((size_t)(WS_CAPT_FLOATS + WS_CAPL_FLOATS) * 4)

#define PIDX(i, c) ((i) * PSTR + (c) * OUTL)

__device__ __forceinline__ float4 ld4(const float* p) { return *reinterpret_cast<const float4*>(p); }
__device__ __forceinline__ void st4(float* p, float4 v) { *reinterpret_cast<float4*>(p) = v; }
__device__ __forceinline__ float dot4(float4 a, float4 b) { return a.x*b.x + a.y*b.y + a.z*b.z + a.w*b.w; }
__device__ __forceinline__ float tanh_fast(float x) {
  float e = __expf(2.f * x);                 // inf for large x -> result 1.0 (correct)
  return 1.f - 2.f / (e + 1.f);
}

// ---- pre-kernel 1: transpose edges [k][g] -> [g][k], pack local (src<<8|dst)
__global__ void prek_edges(const int* __restrict__ esrc, const int* __restrict__ edst,
                           unsigned int* __restrict__ wsE) {
  __shared__ unsigned int t[64][65];
  const int kb = blockIdx.x % (EPG / 64);
  const int gb = blockIdx.x / (EPG / 64);
  const int lane = threadIdx.x & 63;
  const int row  = threadIdx.x >> 6;
  #pragma unroll
  for (int r = row; r < 64; r += 4) {
    int k = kb * 64 + r;
    int g = gb * 64 + lane;
    if (g < NGRAPH) {
      int idx = k * NGRAPH + g;
      int si = esrc[idx] - g * NPG;
      int di = edst[idx] - g * NPG;
      t[r][lane] = (unsigned int)((si << 8) | di);
    }
  }
  __syncthreads();
  #pragma unroll
  for (int r = row; r < 64; r += 4) {
    int g = gb * 64 + r;
    int k = kb * 64 + lane;
    if (g < NGRAPH) wsE[(size_t)g * EPG + k] = t[lane][r];
  }
}

// ---- pre-kernel 2: Wcap[c][e][l] -> capT[c][lq][e][4] + capL[c][e] (l=96)
__global__ void prek_cap(const float* __restrict__ Wcap, float* __restrict__ capT,
                         float* __restrict__ capL) {
  int o = blockIdx.x * 256 + threadIdx.x;
  if (o < WS_CAPT_FLOATS) {
    int j  = o & 3;
    int e  = (o >> 2) & 15;
    int lq = (o >> 6) % LQ;
    int c  = (o >> 6) / LQ;
    capT[o] = Wcap[(c * OUTL + e) * INL + lq * 4 + j];
  }
  if (o < WS_CAPL_FLOATS) capL[o] = Wcap[o * INL + 96];
}

// ======= v8: fused-LDS (no featG) + instruction diet + 128-VGPR budget =======
struct SMemV8 {
  float feat[NPG * FSTR];                // 40000 : cols l*32+f (l=0..2), col 96; lives whole kernel
  union {
    struct {                             // phase A
      float hs[(NPG + 1) * XSTR];        // 14544 (row 100 = zeros for CSR padding)
      float W[NF * NF];                  // 4096
      float bias2[2][NF];                // 256
      unsigned short csr16[CSRMAX];      // 3840 : src*XSTR offsets, padded to x4 per dst
      int cnt[NPG];                      // 400
      float dinv[NPG];                   // 400
      int ptr[NPG + 1];                  // 404
    } a;                                 // 23940 B
    struct {                             // phase B (A dead after top-30)
      float priors[KP * PSTR];           // 19680
      float prsq[KP * NC];               // 1200
      float simbuf[KP * NC];             // 1200
      float outv[NC * OUTL];             // 640
    } b;                                 // 22720 B
  } u;
  int order[KP];                         // 120
};                                       // 64060 B -> 2 blocks/CU

__global__ __launch_bounds__(NTV, 4) void gcn_caps_v8(
    const float* __restrict__ x,
    const unsigned int* __restrict__ wsE,
    const float* __restrict__ W1, const float* __restrict__ b1,
    const float* __restrict__ W2, const float* __restrict__ b2,
    const float* __restrict__ W3, const float* __restrict__ b3,
    const float* __restrict__ W4, const float* __restrict__ b4,
    const float* __restrict__ capT, const float* __restrict__ capL,
    float* __restrict__ out)
{
  extern __shared__ char smraw[];
  SMemV8& s = *reinterpret_cast<SMemV8*>(smraw);
  const int g = blockIdx.x;
  const int tid = threadIdx.x;

  // A1: zero counters + hs pad-row, stage W1/b1
  if (tid < NPG) s.u.a.cnt[tid] = 0;
  if (tid >= 128 && tid < 128 + XSTR) s.u.a.hs[ZROW + (tid - 128)] = 0.f;
  for (int i = tid; i < NF * NF; i += NTV) s.u.a.W[i] = W1[i];
  if (tid < NF) s.u.a.bias2[0][tid] = b1[tid];
  __syncthreads();

  // A2: degree count (coalesced wsE read)
  const unsigned int* eg = wsE + (size_t)g * EPG;
  for (int k = tid; k < EPG; k += NTV) atomicAdd(&s.u.a.cnt[eg[k] & 0xFF], 1);
  __syncthreads();

  // A3: exclusive scan over PADDED counts (multiple of 4 per node)
  if (tid < 64) {
    int j = tid;
    int r0 = (2 * j < NPG) ? s.u.a.cnt[2 * j] : 0;
    int r1 = (2 * j + 1 < NPG) ? s.u.a.cnt[2 * j + 1] : 0;
    int p0 = (r0 + 3) & ~3, p1 = (r1 + 3) & ~3;
    int t = p0 + p1;
    int run = t;
    #pragma unroll
    for (int off = 1; off < 64; off <<= 1) {
      int u = __shfl_up(run, off);
      if (j >= off) run += u;
    }
    int excl = run - t;
    if (2 * j < NPG) s.u.a.ptr[2 * j] = excl;
    if (2 * j + 1 < NPG) s.u.a.ptr[2 * j + 1] = excl + p0;
    if (j == 63) s.u.a.ptr[NPG] = run;
  }
  __syncthreads();
  if (tid < NPG) {
    int deg = s.u.a.cnt[tid];
    int p0 = s.u.a.ptr[tid], p1 = s.u.a.ptr[tid + 1];
    s.u.a.dinv[tid] = rsqrtf((float)deg + 1.0f);
    s.u.a.cnt[tid] = p0;                       // fill cursor
    for (int j = p0 + deg; j < p1; ++j) s.u.a.csr16[j] = (unsigned short)ZROW;  // pad -> zero row
  }
  __syncthreads();

  // A4: CSR fill (offsets pre-multiplied by XSTR)
  for (int k = tid; k < EPG; k += NTV) {
    unsigned int p = eg[k];
    int pos = atomicAdd(&s.u.a.cnt[p & 0xFF], 1);
    s.u.a.csr16[pos] = (unsigned short)(((p >> 8) & 0xFF) * XSTR);
  }
  __syncthreads();

  const float4* xr = reinterpret_cast<const float4*>(x + (size_t)g * NPG * NF);

  // A5: three 32-wide GCN layers
  for (int l = 0; l < 3; ++l) {
    // GEMM, 4-node register-blocked: thread = (nd in [0,25), cq); nodes nd+25n
    if (tid < 25 * 8) {
      int nd = tid >> 3, cq = tid & 7;
      float4 ac0 = make_float4(0,0,0,0), ac1 = ac0, ac2 = ac0, ac3 = ac0;
      #pragma unroll
      for (int kq = 0; kq < 8; ++kq) {
        float4 a0, a1, a2, a3;
        if (l == 0) {
          a0 = xr[(nd     ) * 8 + kq]; a1 = xr[(nd + 25) * 8 + kq];
          a2 = xr[(nd + 50) * 8 + kq]; a3 = xr[(nd + 75) * 8 + kq];
        } else {
          int cb = (l - 1) * NF + kq * 4;
          a0 = ld4(&s.feat[(nd     ) * FSTR + cb]);
          a1 = ld4(&s.feat[(nd + 25) * FSTR + cb]);
          a2 = ld4(&s.feat[(nd + 50) * FSTR + cb]);
          a3 = ld4(&s.feat[(nd + 75) * FSTR + cb]);
        }
        const float v0[4] = {a0.x, a0.y, a0.z, a0.w};
        const float v1[4] = {a1.x, a1.y, a1.z, a1.w};
        const float v2[4] = {a2.x, a2.y, a2.z, a2.w};
        const float v3[4] = {a3.x, a3.y, a3.z, a3.w};
        #pragma unroll
        for (int j = 0; j < 4; ++j) {
          float4 w4 = ld4(&s.u.a.W[(kq * 4 + j) * NF + cq * 4]);
          ac0.x += v0[j]*w4.x; ac0.y += v0[j]*w4.y; ac0.z += v0[j]*w4.z; ac0.w += v0[j]*w4.w;
          ac1.x += v1[j]*w4.x; ac1.y += v1[j]*w4.y; ac1.z += v1[j]*w4.z; ac1.w += v1[j]*w4.w;
          ac2.x += v2[j]*w4.x; ac2.y += v2[j]*w4.y; ac2.z += v2[j]*w4.z; ac2.w += v2[j]*w4.w;
          ac3.x += v3[j]*w4.x; ac3.y += v3[j]*w4.y; ac3.z += v3[j]*w4.z; ac3.w += v3[j]*w4.w;
        }
      }
      float d0 = s.u.a.dinv[nd], d1 = s.u.a.dinv[nd + 25];
      float d2 = s.u.a.dinv[nd + 50], d3 = s.u.a.dinv[nd + 75];
      ac0.x*=d0; ac0.y*=d0; ac0.z*=d0; ac0.w*=d0;
      ac1.x*=d1; ac1.y*=d1; ac1.z*=d1; ac1.w*=d1;
      ac2.x*=d2; ac2.y*=d2; ac2.z*=d2; ac2.w*=d2;
      ac3.x*=d3; ac3.y*=d3; ac3.z*=d3; ac3.w*=d3;
      st4(&s.u.a.hs[(nd     ) * XSTR + cq * 4], ac0);
      st4(&s.u.a.hs[(nd + 25) * XSTR + cq * 4], ac1);
      st4(&s.u.a.hs[(nd + 50) * XSTR + cq * 4], ac2);
      st4(&s.u.a.hs[(nd + 75) * XSTR + cq * 4], ac3);
    }
    __syncthreads();

    // prefetch next weights (AGG never reads W)
    if (l == 0) {
      for (int i = tid; i < NF * NF; i += NTV) s.u.a.W[i] = W2[i];
      if (tid < NF) s.u.a.bias2[1][tid] = b2[tid];
    } else if (l == 1) {
      for (int i = tid; i < NF * NF; i += NTV) s.u.a.W[i] = W3[i];
      if (tid < NF) s.u.a.bias2[0][tid] = b3[tid];
    } else {
      if (tid < NF) s.u.a.W[tid] = W4[tid];
      if (tid == NTV - 1) s.u.a.bias2[1][0] = b4[0];
    }

    // AGG: grid-stride 800 items on 512 threads; padded b64-packed CSR gather
    for (int o = tid; o < NPG * 8; o += NTV) {
      int d = o >> 3, fq4 = (o & 7) * 4;
      const float* bc = s.u.a.bias2[l & 1];
      float4 bq = ld4(&bc[fq4]);
      float4 r = ld4(&s.u.a.hs[d * XSTR + fq4]);   // self term
      int p0 = s.u.a.ptr[d], p1 = s.u.a.ptr[d + 1];
      for (int idx = p0; idx < p1; idx += 4) {
        uint2 c2 = *reinterpret_cast<const uint2*>(&s.u.a.csr16[idx]);
        int o0 = c2.x & 0xFFFF, o1 = c2.x >> 16;
        int o2 = c2.y & 0xFFFF, o3 = c2.y >> 16;
        float4 h0 = ld4(&s.u.a.hs[o0 + fq4]);
        float4 h1 = ld4(&s.u.a.hs[o1 + fq4]);
        float4 h2 = ld4(&s.u.a.hs[o2 + fq4]);
        float4 h3 = ld4(&s.u.a.hs[o3 + fq4]);
        r.x += (h0.x + h1.x) + (h2.x + h3.x);
        r.y += (h0.y + h1.y) + (h2.y + h3.y);
        r.z += (h0.z + h1.z) + (h2.z + h3.z);
        r.w += (h0.w + h1.w) + (h2.w + h3.w);
      }
      float di = s.u.a.dinv[d];
      float4 oo;
      oo.x = tanh_fast(di * r.x + bq.x);
      oo.y = tanh_fast(di * r.y + bq.y);
      oo.z = tanh_fast(di * r.z + bq.z);
      oo.w = tanh_fast(di * r.w + bq.w);
      st4(&s.feat[d * FSTR + l * NF + fq4], oo);   // next layer input + capsule features
    }
    __syncthreads();
  }

  // A6: layer 4 (1-wide): input = cols 64..95
  if (tid < NPG) {
    float a = 0.f;
    #pragma unroll
    for (int kq = 0; kq < 8; ++kq)
      a += dot4(ld4(&s.feat[tid * FSTR + 2 * NF + kq * 4]), ld4(&s.u.a.W[kq * 4]));
    s.u.a.hs[tid * XSTR] = a * s.u.a.dinv[tid];
  }
  __syncthreads();
  if (tid < NPG) {
    float r = s.u.a.hs[tid * XSTR];
    int p0 = s.u.a.ptr[tid], p1 = s.u.a.ptr[tid + 1];
    for (int idx = p0; idx < p1; ++idx) r += s.u.a.hs[s.u.a.csr16[idx]];  // pads add hs[ZROW]=0
    s.feat[tid * FSTR + 96] = tanh_fast(s.u.a.dinv[tid] * r + s.u.a.bias2[1][0]);
  }
  __syncthreads();

  // A7: stable top-30 by col96 desc; 4 threads/node, shfl-combined
  if (tid < NPG * 4) {
    int i = tid >> 2, p = tid & 3;
    float vv = s.feat[i * FSTR + 96];
    int j0 = p * 25, j1 = j0 + 25;
    int rank = 0;
    for (int j = j0; j < j1; ++j) {
      float vj = s.feat[j * FSTR + 96];
      rank += (vj > vv) || (vj == vv && j < i);
    }
    rank += __shfl_xor(rank, 1);
    rank += __shfl_xor(rank, 2);
    if (p == 0 && rank < KP) s.order[rank] = i;
  }
  __syncthreads();   // after this, phase-A union area is dead -> phase B may write

  // B2: priors, (c,e)-major, 15-i register blocking; feat read via order[] from LDS
  if (tid < NC * OUTL * 2) {
    int c = tid >> 5;
    int r = tid & 31;
    int e = r >> 1;
    int i0 = (r & 1) * 15;
    int ro[15];
    #pragma unroll
    for (int ii = 0; ii < 15; ++ii) ro[ii] = s.order[i0 + ii] * FSTR;
    float acc[15];
    #pragma unroll
    for (int ii = 0; ii < 15; ++ii) acc[ii] = 0.f;
    for (int lq = 0; lq < LQ; ++lq) {
      float4 w4 = ld4(capT + ((c * LQ + lq) * OUTL + e) * 4);
      #pragma unroll
      for (int ii = 0; ii < 15; ++ii) {
        float4 f4 = ld4(&s.feat[ro[ii] + lq * 4]);
        acc[ii] += dot4(f4, w4);
      }
    }
    float wl = capL[c * OUTL + e];
    #pragma unroll
    for (int ii = 0; ii < 15; ++ii)
      acc[ii] += s.feat[ro[ii] + 96] * wl;
    #pragma unroll
    for (int ii = 0; ii < 15; ++ii)
      s.u.b.priors[PIDX(i0 + ii, c) + e] = acc[ii];
  }
  __syncthreads();

  // B3: pr_sq + out init
  if (tid < KP * NC) {
    int i = tid / NC, c = tid % NC;
    const float* pr = &s.u.b.priors[PIDX(i, c)];
    float a = 0.f;
    #pragma unroll
    for (int eq = 0; eq < 4; ++eq) { float4 p = ld4(pr + eq * 4); a += dot4(p, p); }
    s.u.b.prsq[tid] = a;
  }
  if (tid < NC * OUTL) {
    int c = tid >> 4, e = tid & 15;
    float a = 0.f;
    #pragma unroll
    for (int i = 0; i < KP; ++i) a += s.u.b.priors[PIDX(i, c) + e];
    s.u.b.outv[tid] = a * (1.0f / KP);
  }
  __syncthreads();

  // B4: routing, 2 barriers/iter (softmax merged into update)
  for (int it = 0; it < NITER; ++it) {
    if (tid < KP * NC) {
      int i = tid / NC, c = tid % NC;
      const float* pr = &s.u.b.priors[PIDX(i, c)];
      const float* ov = &s.u.b.outv[c * OUTL];
      float xy = 0.f, oq = 0.f;
      #pragma unroll
      for (int eq = 0; eq < 4; ++eq) {
        float4 p = ld4(pr + eq * 4);
        float4 o = ld4(ov + eq * 4);
        xy += dot4(p, o); oq += dot4(o, o);
      }
      s.u.b.simbuf[tid] = xy / (s.u.b.prsq[tid] + oq - xy);
    }
    __syncthreads();
    if (tid < NC * OUTL) {
      int c = tid >> 4, e = tid & 15;
      float m = -1e30f;
      #pragma unroll
      for (int i = 0; i < KP; ++i) m = fmaxf(m, s.u.b.simbuf[i * NC + c]);
      float ss = 0.f, a = 0.f;
      #pragma unroll
      for (int i = 0; i < KP; ++i) {
        float w = __expf(s.u.b.simbuf[i * NC + c] - m);
        ss += w;
        a += w * s.u.b.priors[PIDX(i, c) + e];
      }
      s.u.b.outv[tid] = a / ss;
    }
    __syncthreads();
  }

  // B5: classes = ||out||
  if (tid < NC) {
    const float* ov = &s.u.b.outv[tid * OUTL];
    float a = 0.f;
    #pragma unroll
    for (int eq = 0; eq < 4; ++eq) { float4 o = ld4(ov + eq * 4); a += dot4(o, o); }
    out[(size_t)g * NC + tid] = sqrtf(a);
  }
}

// ==================== fused fallback (proven R4 kernel, 81KB LDS) ====================
struct SMemF {
  float feat[NPG * FSTR];
  union {
    unsigned short epack[EPG];
    float priors[KP * PSTR];
  } u;
  union {
    float hs[NPG * HSTR];
    struct {
      float prsq[KP * NC];
      float simbuf[KP * NC];
      float outv[NC * OUTL];
      float smax[NC];
      float ssum[NC];
      int   order[KP];
    } r;
  } v;
  float W[NF * NF];
  float bias2[2][NF];
  unsigned char csr[EPG];
  int ptr[NPG + 1];
  int cnt[NPG];
  float dinv[NPG];
};

template <bool WSC>
__global__ __launch_bounds__(NTF, 8) void gcn_caps_fused(
    const float* __restrict__ x,
    const int* __restrict__ esrc, const int* __restrict__ edst,
    const float* __restrict__ W1, const float* __restrict__ b1,
    const float* __restrict__ W2, const float* __restrict__ b2,
    const float* __restrict__ W3, const float* __restrict__ b3,
    const float* __restrict__ W4, const float* __restrict__ b4,
    const float* __restrict__ Wcap,
    const float* __restrict__ capT, const float* __restrict__ capL,
    float* __restrict__ out)
{
  extern __shared__ char smem_raw[];
  SMemF& s = *reinterpret_cast<SMemF*>(smem_raw);
  const int g = blockIdx.x;
  const int tid = threadIdx.x;

  if (tid < NPG) s.cnt[tid] = 0;
  for (int i = tid; i < NF * NF; i += NTF) s.W[i] = W1[i];
  if (tid < NF) s.bias2[0][tid] = b1[tid];
  __syncthreads();

  for (int k = tid; k < EPG; k += NTF) {
    int si = esrc[g + k * NGRAPH] - g * NPG;
    int di = edst[g + k * NGRAPH] - g * NPG;
    s.u.epack[k] = (unsigned short)((si << 8) | di);
    atomicAdd(&s.cnt[di], 1);
  }
  __syncthreads();

  if (tid < 64) {
    int j = tid;
    int a0 = (2 * j < NPG) ? s.cnt[2 * j] : 0;
    int a1 = (2 * j + 1 < NPG) ? s.cnt[2 * j + 1] : 0;
    int t = a0 + a1;
    int run = t;
    #pragma unroll
    for (int off = 1; off < 64; off <<= 1) {
      int u = __shfl_up(run, off);
      if (j >= off) run += u;
    }
    int excl = run - t;
    if (2 * j < NPG) s.ptr[2 * j] = excl;
    if (2 * j + 1 < NPG) s.ptr[2 * j + 1] = excl + a0;
    if (j == 63) s.ptr[NPG] = run;
  }
  __syncthreads();
  if (tid < NPG) {
    s.dinv[tid] = rsqrtf((float)s.cnt[tid] + 1.0f);
    s.cnt[tid] = s.ptr[tid];
  }
  __syncthreads();

  for (int k = tid; k < EPG; k += NTF) {
    int pk = s.u.epack[k];
    int pos = atomicAdd(&s.cnt[pk & 0xFF], 1);
    s.csr[pos] = (unsigned char)(pk >> 8);
  }
  __syncthreads();

  const float4* xr = reinterpret_cast<const float4*>(x + (size_t)g * NPG * NF);
  for (int l = 0; l < 3; ++l) {
    if (tid < NPG * 8) {
      int node = tid >> 3, cq = tid & 7;
      float4 acc = make_float4(0.f, 0.f, 0.f, 0.f);
      #pragma unroll
      for (int kq = 0; kq < 8; ++kq) {
        float4 a4 = (l == 0) ? xr[node * 8 + kq]
                             : ld4(&s.feat[node * FSTR + (l - 1) * NF + kq * 4]);
        const float av[4] = {a4.x, a4.y, a4.z, a4.w};
        #pragma unroll
        for (int j = 0; j < 4; ++j) {
          float4 w4 = ld4(&s.W[(kq * 4 + j) * NF + cq * 4]);
          acc.x += av[j] * w4.x; acc.y += av[j] * w4.y;
          acc.z += av[j] * w4.z; acc.w += av[j] * w4.w;
        }
      }
      float di = s.dinv[node];
      acc.x *= di; acc.y *= di; acc.z *= di; acc.w *= di;
      st4(&s.v.hs[node * HSTR + ((cq ^ (node >> 3)) & 7) * 4], acc);
    }
    __syncthreads();

    if (l == 0) {
      for (int i = tid; i < NF * NF; i += NTF) s.W[i] = W2[i];
      if (tid < NF) s.bias2[1][tid] = b2[tid];
    } else if (l == 1) {
      for (int i = tid; i < NF * NF; i += NTF) s.W[i] = W3[i];
      if (tid < NF) s.bias2[0][tid] = b3[tid];
    } else {
      if (tid < NF) s.W[tid] = W4[tid];
      if (tid == NTF - 1) s.bias2[1][0] = b4[0];
    }

    if (tid < NPG * 8) {
      int d = tid >> 3, fq = tid & 7;
      const float* bc = s.bias2[l & 1];
      float4 b4q = ld4(&bc[fq * 4]);
      float4 r = ld4(&s.v.hs[d * HSTR + ((fq ^ (d >> 3)) & 7) * 4]);
      int p0 = s.ptr[d], p1 = s.ptr[d + 1];
      int idx = p0;
      for (; idx + 1 < p1; idx += 2) {
        int sc0 = s.csr[idx], sc1 = s.csr[idx + 1];
        float4 h0 = ld4(&s.v.hs[sc0 * HSTR + ((fq ^ (sc0 >> 3)) & 7) * 4]);
        float4 h1 = ld4(&s.v.hs[sc1 * HSTR + ((fq ^ (sc1 >> 3)) & 7) * 4]);
        r.x += h0.x + h1.x; r.y += h0.y + h1.y;
        r.z += h0.z + h1.z; r.w += h0.w + h1.w;
      }
      if (idx < p1) {
        int sc = s.csr[idx];
        float4 hq = ld4(&s.v.hs[sc * HSTR + ((fq ^ (sc >> 3)) & 7) * 4]);
        r.x += hq.x; r.y += hq.y; r.z += hq.z; r.w += hq.w;
      }
      float di = s.dinv[d];
      float4 o;
      o.x = tanh_fast(di * r.x + b4q.x);
      o.y = tanh_fast(di * r.y + b4q.y);
      o.z = tanh_fast(di * r.z + b4q.z);
      o.w = tanh_fast(di * r.w + b4q.w);
      st4(&s.feat[d * FSTR + l * NF + fq * 4], o);
    }
    __syncthreads();
  }

  float* hsf = s.v.hs;
  if (tid < NPG) {
    float a = 0.f;
    #pragma unroll
    for (int kq = 0; kq < 8; ++kq)
      a += dot4(ld4(&s.feat[tid * FSTR + 64 + kq * 4]), ld4(&s.W[kq * 4]));
    hsf[tid] = a * s.dinv[tid];
  }
  __syncthreads();
  if (tid < NPG) {
    float r = hsf[tid];
    int p0 = s.ptr[tid], p1 = s.ptr[tid + 1];
    for (int idx = p0; idx < p1; ++idx) r += hsf[s.csr[idx]];
    s.feat[tid * FSTR + 96] = tanh_fast(s.dinv[tid] * r + s.bias2[1][0]);
  }
  __syncthreads();

  if (tid < NPG * 8) {
    int i = tid >> 3, p = tid & 7;
    float vv = s.feat[i * FSTR + 96];
    int j0 = p * 13, j1 = min(NPG, j0 + 13);
    int rank = 0;
    for (int j = j0; j < j1; ++j) {
      float vj = s.feat[j * FSTR + 96];
      rank += (vj > vv) || (vj == vv && j < i);
    }
    rank += __shfl_xor(rank, 1);
    rank += __shfl_xor(rank, 2);
    rank += __shfl_xor(rank, 4);
    if (p == 0 && rank < KP) s.v.r.order[rank] = i;
  }
  __syncthreads();

  if (tid < KP * OUTL) {
    int i = tid >> 4, e = tid & 15;
    int row = s.v.r.order[i] * FSTR;
    float acc[NC];
    #pragma unroll
    for (int c = 0; c < NC; ++c) acc[c] = 0.f;
    if (WSC) {
      for (int lq = 0; lq < LQ; ++lq) {
        float4 f4 = ld4(&s.feat[row + lq * 4]);
        #pragma unroll
        for (int c = 0; c < NC; ++c) {
          float4 w4 = ld4(capT + ((c * LQ + lq) * OUTL + e) * 4);
          acc[c] += dot4(f4, w4);
        }
      }
      float xl = s.feat[row + 96];
      #pragma unroll
      for (int c = 0; c < NC; ++c) acc[c] += xl * capL[c * OUTL + e];
    } else {
      for (int c = 0; c < NC; ++c) {
        float a = 0.f;
        for (int l = 0; l < INL; ++l) a += s.feat[row + l] * Wcap[(c * OUTL + e) * INL + l];
        acc[c] = a;
      }
    }
    #pragma unroll
    for (int c = 0; c < NC; ++c) s.u.priors[PIDX(i, c) + e] = acc[c];
  }
  __syncthreads();

  if (tid < KP * NC) {
    int i = tid / NC, c = tid % NC;
    const float* pr = &s.u.priors[PIDX(i, c)];
    float a = 0.f;
    #pragma unroll
    for (int eq = 0; eq < 4; ++eq) { float4 p = ld4(pr + eq * 4); a += dot4(p, p); }
    s.v.r.prsq[tid] = a;
  }
  if (tid < NC * OUTL) {
    int c = tid >> 4, e = tid & 15;
    float a = 0.f;
    #pragma unroll
    for (int i = 0; i < KP; ++i) a += s.u.priors[PIDX(i, c) + e];
    s.v.r.outv[tid] = a * (1.0f / KP);
  }
  __syncthreads();

  for (int it = 0; it < NITER; ++it) {
    if (tid < KP * NC) {
      int i = tid / NC, c = tid % NC;
      const float* pr = &s.u.priors[PIDX(i, c)];
      const float* ov = &s.v.r.outv[c * OUTL];
      float xy = 0.f, oq = 0.f;
      #pragma unroll
      for (int eq = 0; eq < 4; ++eq) {
        float4 p = ld4(pr + eq * 4);
        float4 o = ld4(ov + eq * 4);
        xy += dot4(p, o); oq += dot4(o, o);
      }
      s.v.r.simbuf[tid] = xy / (s.v.r.prsq[tid] + oq - xy);
    }
    __syncthreads();
    if (tid < NC) {
      float m = -1e30f;
      #pragma unroll
      for (int i = 0; i < KP; ++i) m = fmaxf(m, s.v.r.simbuf[i * NC + tid]);
      float ss = 0.f;
      #pragma unroll
      for (int i = 0; i < KP; ++i) ss += __expf(s.v.r.simbuf[i * NC + tid] - m);
      s.v.r.smax[tid] = m;
      s.v.r.ssum[tid] = 1.f / ss;
    }
    __syncthreads();
    if (tid < NC * OUTL) {
      int c = tid >> 4, e = tid & 15;
      float m = s.v.r.smax[c], is = s.v.r.ssum[c], a = 0.f;
      #pragma unroll
      for (int i = 0; i < KP; ++i)
        a += __expf(s.v.r.simbuf[i * NC + c] - m) * s.u.priors[PIDX(i, c) + e];
      s.v.r.outv[tid] = a * is;
    }
    __syncthreads();
  }

  if (tid < NC) {
    const float* ov = &s.v.r.outv[tid * OUTL];
    float a = 0.f;
    #pragma unroll
    for (int eq = 0; eq < 4; ++eq) { float4 o = ld4(ov + eq * 4); a += dot4(o, o); }
    out[(size_t)g * NC + tid] = sqrtf(a);
  }
}

extern "C" void kernel_launch(void* const* d_in, const int* in_sizes, int n_in,
                              void* d_out, int out_size, void* d_ws, size_t ws_size,
                              hipStream_t stream) {
  const float* x    = (const float*)d_in[0];
  const int*   esrc = (const int*)d_in[1];
  const int*   edst = (const int*)d_in[2];
  const float* W1 = (const float*)d_in[4];
  const float* b1 = (const float*)d_in[5];
  const float* W2 = (const float*)d_in[6];
  const float* b2 = (const float*)d_in[7];
  const float* W3 = (const float*)d_in[8];
  const float* b3 = (const float*)d_in[9];
  const float* W4 = (const float*)d_in[10];
  const float* b4 = (const float*)d_in[11];
  const float* Wcap = (const float*)d_in[12];
  float* outp = (float*)d_out;

  const bool wse = ws_size >= WS_EDGES_BYTES + WS_CAP_BYTES;
  const bool wsc = ws_size >= WS_CAP_BYTES;

  unsigned int* wsE = (unsigned int*)d_ws;
  float* capT = wse ? (float*)((char*)d_ws + WS_EDGES_BYTES) : (float*)d_ws;
  float* capL = capT + WS_CAPT_FLOATS;

  if (wse) {
    (void)hipFuncSetAttribute((const void*)gcn_caps_v8,
                              hipFuncAttributeMaxDynamicSharedMemorySize, (int)sizeof(SMemV8));
    prek_edges<<<(EPG / 64) * 16, 256, 0, stream>>>(esrc, edst, wsE);
    prek_cap<<<(WS_CAPT_FLOATS + 255) / 256, 256, 0, stream>>>(Wcap, capT, capL);
    gcn_caps_v8<<<NGRAPH, NTV, sizeof(SMemV8), stream>>>(
        x, wsE, W1, b1, W2, b2, W3, b3, W4, b4, capT, capL, outp);
  } else if (wsc) {
    (void)hipFuncSetAttribute((const void*)gcn_caps_fused<true>,
                              hipFuncAttributeMaxDynamicSharedMemorySize, (int)sizeof(SMemF));
    prek_cap<<<(WS_CAPT_FLOATS + 255) / 256, 256, 0, stream>>>(Wcap, capT, capL);
    gcn_caps_fused<true><<<NGRAPH, NTF, sizeof(SMemF), stream>>>(
        x, esrc, edst, W1, b1, W2, b2, W3, b3, W4, b4, Wcap, capT, capL, outp);
  } else {
    (void)hipFuncSetAttribute((const void*)gcn_caps_fused<false>,
                              hipFuncAttributeMaxDynamicSharedMemorySize, (int)sizeof(SMemF));
    gcn_caps_fused<false><<<NGRAPH, NTF, sizeof(SMemF), stream>>>(
        x, esrc, edst, W1, b1, W2, b2, W3, b3, W4, b4, Wcap, capT, capL, outp);
  }
}